// Round 2
// baseline (1023.842 us; speedup 1.0000x reference)
//
#include <hip/hip_runtime.h>
#include <hip/hip_bf16.h>
#include <stdint.h>

// Problem constants (from reference)
#define B_ 8
#define T_ 1500
#define H_ 1280
#define HM1 1279
#define OUT_ 4096
#define MTOK 375
#define MROWS (B_*MTOK)   // 3000

// K1: alphas = sigmoid(audio[:,:,H-1]); pred = sum; alphas *= num_tokens/pred.
// Also writes pred (fp32) to out tail, and inits lo/hi range arrays.
__global__ __launch_bounds__(256) void k1_alphas(
    const float* __restrict__ audio, const int* __restrict__ num_tokens,
    float* __restrict__ alphas, float* __restrict__ pred_out,
    int* __restrict__ lo, int* __restrict__ hi)
{
    int b = blockIdx.x;
    int tid = threadIdx.x;
    // init ranges for this batch
    for (int m = tid; m < MTOK; m += 256) { lo[b*MTOK+m] = T_; hi[b*MTOK+m] = 0; }

    float sig[6];
    float s = 0.f;
    #pragma unroll
    for (int i = 0; i < 6; ++i) {
        int t = tid + i*256;
        sig[i] = 0.f;
        if (t < T_) {
            float x = audio[((size_t)b*T_ + t)*H_ + (H_-1)];
            sig[i] = 1.f / (1.f + expf(-x));
            s += sig[i];
        }
    }
    __shared__ float red[256];
    red[tid] = s; __syncthreads();
    for (int off = 128; off > 0; off >>= 1) {
        if (tid < off) red[tid] += red[tid+off];
        __syncthreads();
    }
    __shared__ float scale_sh;
    if (tid == 0) {
        float pred = red[0];
        pred_out[b] = pred;
        scale_sh = (float)num_tokens[b] / pred;
    }
    __syncthreads();
    float scale = scale_sh;
    #pragma unroll
    for (int i = 0; i < 6; ++i) {
        int t = tid + i*256;
        if (t < T_) alphas[b*T_ + t] = sig[i] * scale;
    }
}

// K2: sequential CIF scan per batch (exact fp32 order as reference).
// Emits tok0/w0 (col set at old token) and tok1/w1 (remainder add at new token),
// plus [lo,hi) t-range per token (written at fire transitions).
__global__ __launch_bounds__(64) void k2_scan(
    const float* __restrict__ alphas, const int* __restrict__ num_tokens,
    int* __restrict__ tok0, float* __restrict__ w0a,
    int* __restrict__ tok1, float* __restrict__ w1a,
    int* __restrict__ lo, int* __restrict__ hi)
{
    __shared__ float al[B_*T_];  // 48 KB
    for (int i = threadIdx.x; i < B_*T_; i += 64) al[i] = alphas[i];
    __syncthreads();
    int b = threadIdx.x;
    if (b >= B_) return;
    int nm1 = num_tokens[b] - 1;
    float integrate = 0.f;
    int tok = 0;
    lo[b*MTOK + 0] = 0;
    for (int t = 0; t < T_; ++t) {
        float alpha = al[b*T_ + t];
        float alpha_needed = 1.f - integrate;
        integrate += alpha;
        bool ready = (integrate >= 1.f);
        float a_int = ready ? alpha_needed : alpha;
        float n_int = ready ? (integrate - 1.f) : integrate;
        float rem = alpha - a_int;
        int ntok = ready ? min(tok + 1, nm1) : tok;
        int i0 = b*T_ + t;
        tok0[i0] = tok;  w0a[i0] = a_int;
        float w1v = (t < T_-1) ? rem : 0.f;
        tok1[i0] = ntok; w1a[i0] = w1v;
        if (ntok != tok) {             // token advanced: close old range, open new
            hi[b*MTOK + tok] = t + 1;
            lo[b*MTOK + ntok] = t;     // w1 lands at column t of new token
        }
        integrate = n_int;
        tok = ntok;
    }
    hi[b*MTOK + tok] = T_;
}

// K3: sparse pooling h1[b,m,:] = sum_t w[b,m,t] * audio[b,t,0:1279]
__global__ __launch_bounds__(256) void k3_pool(
    const float* __restrict__ audio,
    const int* __restrict__ tok0, const float* __restrict__ w0a,
    const int* __restrict__ tok1, const float* __restrict__ w1a,
    const int* __restrict__ lo, const int* __restrict__ hi,
    float* __restrict__ h1)
{
    int bm = blockIdx.x;
    int b = bm / MTOK, m = bm % MTOK;
    int l = lo[bm], h = hi[bm];
    int tid = threadIdx.x;
    float acc[5] = {0.f,0.f,0.f,0.f,0.f};
    for (int t = l; t < h; ++t) {
        int i0 = b*T_ + t;
        float w = 0.f;
        if (tok0[i0] == m) w += w0a[i0];
        if (tok1[i0] == m) w += w1a[i0];
        if (w != 0.f) {
            const float* row = audio + (size_t)i0 * H_;
            #pragma unroll
            for (int i = 0; i < 5; ++i) {
                int d = tid + i*256;
                if (d < HM1) acc[i] += w * row[d];
            }
        }
    }
    float* dst = h1 + (size_t)bm * HM1;
    #pragma unroll
    for (int i = 0; i < 5; ++i) {
        int d = tid + i*256;
        if (d < HM1) dst[d] = acc[i];
    }
}

// Tiled fp32 GEMM: C[M,N] = A[M,K] @ B[K,N] + bias[N].  64x64 tile, 4x4 microtile.
__global__ __launch_bounds__(256) void gemm_bias(
    const float* __restrict__ A, const float* __restrict__ B,
    const float* __restrict__ bias, float* __restrict__ C,
    int M, int N, int K, int lda, int ldb, int ldc)
{
    __shared__ float As[16][68];   // [k][m], padded
    __shared__ float Bs[16][68];   // [k][n], padded
    const int tid = threadIdx.x;
    const int tx = tid & 15;       // n-group
    const int ty = tid >> 4;       // m-group
    const int m0 = blockIdx.y * 64;
    const int n0 = blockIdx.x * 64;
    const int ka = tid & 15, ma = tid >> 4;   // A staging
    const int nb = tid & 63, kb = tid >> 6;   // B staging
    float acc[4][4] = {};
    for (int k0 = 0; k0 < K; k0 += 16) {
        #pragma unroll
        for (int p = 0; p < 4; ++p) {
            int m = m0 + ma + p*16;
            int k = k0 + ka;
            As[ka][ma + p*16] = (m < M && k < K) ? A[(size_t)m*lda + k] : 0.f;
        }
        #pragma unroll
        for (int p = 0; p < 4; ++p) {
            int k = k0 + kb + p*4;
            Bs[kb + p*4][nb] = (k < K) ? B[(size_t)k*ldb + (n0 + nb)] : 0.f;
        }
        __syncthreads();
        #pragma unroll
        for (int kk = 0; kk < 16; ++kk) {
            float4 a4 = *(const float4*)&As[kk][ty*4];
            float4 b4 = *(const float4*)&Bs[kk][tx*4];
            float a[4] = {a4.x, a4.y, a4.z, a4.w};
            float bv[4] = {b4.x, b4.y, b4.z, b4.w};
            #pragma unroll
            for (int i = 0; i < 4; ++i)
                #pragma unroll
                for (int j = 0; j < 4; ++j)
                    acc[i][j] += a[i] * bv[j];
        }
        __syncthreads();
    }
    #pragma unroll
    for (int i = 0; i < 4; ++i) {
        int m = m0 + ty*4 + i;
        if (m >= M) continue;
        int n = n0 + tx*4;
        float4 o;
        o.x = acc[i][0] + bias[n+0];
        o.y = acc[i][1] + bias[n+1];
        o.z = acc[i][2] + bias[n+2];
        o.w = acc[i][3] + bias[n+3];
        *(float4*)&C[(size_t)m*ldc + n] = o;
    }
}

// K5: in-place RMSNorm over rows of h2 [MROWS,1280], scale by rms_w
__global__ __launch_bounds__(256) void k5_rmsnorm(
    float* __restrict__ h2, const float* __restrict__ rms_w)
{
    int row = blockIdx.x;
    float* p = h2 + (size_t)row * H_;
    int tid = threadIdx.x;
    float v[5];
    float s = 0.f;
    #pragma unroll
    for (int i = 0; i < 5; ++i) {
        v[i] = p[tid + i*256];
        s += v[i] * v[i];
    }
    __shared__ float red[256];
    red[tid] = s; __syncthreads();
    for (int off = 128; off > 0; off >>= 1) {
        if (tid < off) red[tid] += red[tid+off];
        __syncthreads();
    }
    float rms = sqrtf(red[0] / (float)H_ + 1e-6f);
    float inv = 1.f / rms;
    #pragma unroll
    for (int i = 0; i < 5; ++i) {
        int d = tid + i*256;
        p[d] = v[i] * inv * rms_w[d];
    }
}

extern "C" void kernel_launch(void* const* d_in, const int* in_sizes, int n_in,
                              void* d_out, int out_size, void* d_ws, size_t ws_size,
                              hipStream_t stream) {
    (void)in_sizes; (void)n_in; (void)out_size; (void)ws_size;
    const float* audio      = (const float*)d_in[0];
    const int*   num_tokens = (const int*)d_in[1];
    const float* rms_w      = (const float*)d_in[2];
    const float* cif_w      = (const float*)d_in[3];
    const float* cif_b      = (const float*)d_in[4];
    const float* text_w     = (const float*)d_in[5];
    const float* text_b     = (const float*)d_in[6];

    float* out  = (float*)d_out;                   // fp32 output
    float* pred = out + (size_t)MROWS * OUT_;      // pred_num_tokens tail (8 floats)

    char* ws = (char*)d_ws;
    float* alphas = (float*)(ws + 0);          // 48000 B
    float* w0a    = (float*)(ws + 48000);
    float* w1a    = (float*)(ws + 96000);
    int*   tok0   = (int*)  (ws + 144000);
    int*   tok1   = (int*)  (ws + 192000);
    int*   lo     = (int*)  (ws + 240000);     // 12000 B
    int*   hi     = (int*)  (ws + 252000);
    float* h1     = (float*)(ws + 264192);     // [3000][1279] = 15,348,000 B
    float* h2     = (float*)(ws + 15612416);   // [3000][1280] = 15,360,000 B

    k1_alphas<<<B_, 256, 0, stream>>>(audio, num_tokens, alphas, pred, lo, hi);
    k2_scan<<<1, 64, 0, stream>>>(alphas, num_tokens, tok0, w0a, tok1, w1a, lo, hi);
    k3_pool<<<MROWS, 256, 0, stream>>>(audio, tok0, w0a, tok1, w1a, lo, hi, h1);
    // cif_proj: h2 = h1[3000x1279] @ cif_w[1279x1280] + cif_b
    gemm_bias<<<dim3(H_/64, (MROWS+63)/64), 256, 0, stream>>>(
        h1, cif_w, cif_b, h2, MROWS, H_, HM1, HM1, H_, H_);
    k5_rmsnorm<<<MROWS, 256, 0, stream>>>(h2, rms_w);
    // text_proj: out = h2[3000x1280] @ text_w[1280x4096] + text_b
    gemm_bias<<<dim3(OUT_/64, (MROWS+63)/64), 256, 0, stream>>>(
        h2, text_w, text_b, out, MROWS, OUT_, H_, OUT_, OUT_, OUT_);
}

// Round 3
// 460.199 us; speedup vs baseline: 2.2248x; 2.2248x over previous
//
#include <hip/hip_runtime.h>
#include <hip/hip_bf16.h>
#include <stdint.h>

// Problem constants (from reference)
#define B_ 8
#define T_ 1500
#define H_ 1280
#define HM1 1279
#define OUT_ 4096
#define MTOK 375
#define MROWS (B_*MTOK)   // 3000
#define KPAD 1280         // shared K for both GEMMs (cif K=1279 zero-padded)

typedef __attribute__((ext_vector_type(8))) short bf16x8;  // 8 bf16 = 4 VGPRs
typedef __attribute__((ext_vector_type(4))) float f32x4;

static __device__ __forceinline__ unsigned short f2bf(float f) {
    unsigned int x = __float_as_uint(f);
    unsigned int r = (x + 0x7fffu + ((x >> 16) & 1u)) >> 16;
    return (unsigned short)r;
}

static __device__ __forceinline__ void glds16(const unsigned short* g, unsigned short* l) {
    __builtin_amdgcn_global_load_lds(
        (const __attribute__((address_space(1))) void*)g,
        (__attribute__((address_space(3))) void*)l, 16, 0, 0);
}

// K1: alphas = sigmoid(audio[:,:,H-1]); pred = sum; alphas *= num_tokens/pred.
__global__ __launch_bounds__(256) void k1_alphas(
    const float* __restrict__ audio, const int* __restrict__ num_tokens,
    float* __restrict__ alphas, float* __restrict__ pred_out,
    int* __restrict__ lo, int* __restrict__ hi)
{
    int b = blockIdx.x;
    int tid = threadIdx.x;
    for (int m = tid; m < MTOK; m += 256) { lo[b*MTOK+m] = T_; hi[b*MTOK+m] = 0; }

    float sig[6];
    float s = 0.f;
    #pragma unroll
    for (int i = 0; i < 6; ++i) {
        int t = tid + i*256;
        sig[i] = 0.f;
        if (t < T_) {
            float x = audio[((size_t)b*T_ + t)*H_ + (H_-1)];
            sig[i] = 1.f / (1.f + expf(-x));
            s += sig[i];
        }
    }
    __shared__ float red[256];
    red[tid] = s; __syncthreads();
    for (int off = 128; off > 0; off >>= 1) {
        if (tid < off) red[tid] += red[tid+off];
        __syncthreads();
    }
    __shared__ float scale_sh;
    if (tid == 0) {
        float pred = red[0];
        pred_out[b] = pred;
        scale_sh = (float)num_tokens[b] / pred;
    }
    __syncthreads();
    float scale = scale_sh;
    #pragma unroll
    for (int i = 0; i < 6; ++i) {
        int t = tid + i*256;
        if (t < T_) alphas[b*T_ + t] = sig[i] * scale;
    }
}

// K2: sequential CIF scan per batch (exact fp32 order as reference).
__global__ __launch_bounds__(64) void k2_scan(
    const float* __restrict__ alphas, const int* __restrict__ num_tokens,
    int* __restrict__ tok0, float* __restrict__ w0a,
    int* __restrict__ tok1, float* __restrict__ w1a,
    int* __restrict__ lo, int* __restrict__ hi)
{
    __shared__ float al[B_*T_];  // 48 KB
    for (int i = threadIdx.x; i < B_*T_; i += 64) al[i] = alphas[i];
    __syncthreads();
    int b = threadIdx.x;
    if (b >= B_) return;
    int nm1 = num_tokens[b] - 1;
    float integrate = 0.f;
    int tok = 0;
    lo[b*MTOK + 0] = 0;
    for (int t = 0; t < T_; ++t) {
        float alpha = al[b*T_ + t];
        float alpha_needed = 1.f - integrate;
        integrate += alpha;
        bool ready = (integrate >= 1.f);
        float a_int = ready ? alpha_needed : alpha;
        float n_int = ready ? (integrate - 1.f) : integrate;
        float rem = alpha - a_int;
        int ntok = ready ? min(tok + 1, nm1) : tok;
        int i0 = b*T_ + t;
        tok0[i0] = tok;  w0a[i0] = a_int;
        float w1v = (t < T_-1) ? rem : 0.f;
        tok1[i0] = ntok; w1a[i0] = w1v;
        if (ntok != tok) {
            hi[b*MTOK + tok] = t + 1;
            lo[b*MTOK + ntok] = t;
        }
        integrate = n_int;
        tok = ntok;
    }
    hi[b*MTOK + tok] = T_;
}

// K3: sparse pooling -> h1b bf16 [MROWS][KPAD], col 1279 = 0
__global__ __launch_bounds__(256) void k3_pool(
    const float* __restrict__ audio,
    const int* __restrict__ tok0, const float* __restrict__ w0a,
    const int* __restrict__ tok1, const float* __restrict__ w1a,
    const int* __restrict__ lo, const int* __restrict__ hi,
    unsigned short* __restrict__ h1b)
{
    int bm = blockIdx.x;
    int b = bm / MTOK, m = bm % MTOK;
    int l = lo[bm], h = hi[bm];
    int tid = threadIdx.x;
    float acc[5] = {0.f,0.f,0.f,0.f,0.f};
    for (int t = l; t < h; ++t) {
        int i0 = b*T_ + t;
        float w = 0.f;
        if (tok0[i0] == m) w += w0a[i0];
        if (tok1[i0] == m) w += w1a[i0];
        if (w != 0.f) {
            const float* row = audio + (size_t)i0 * H_;
            #pragma unroll
            for (int i = 0; i < 5; ++i) {
                int d = tid + i*256;
                if (d < HM1) acc[i] += w * row[d];
            }
        }
    }
    unsigned short* dst = h1b + (size_t)bm * KPAD;
    #pragma unroll
    for (int i = 0; i < 5; ++i) {
        int d = tid + i*256;
        dst[d] = (d < HM1) ? f2bf(acc[i]) : (unsigned short)0;
    }
}

// Transpose+convert: dst[c][r] (bf16, r padded to KPAD with 0) = src[r][c] (fp32)
__global__ __launch_bounds__(256) void transpose_f32_bf16(
    const float* __restrict__ src, unsigned short* __restrict__ dst, int R, int C)
{
    __shared__ float tile[32][33];
    int c0 = blockIdx.x * 32, r0 = blockIdx.y * 32;
    int lx = threadIdx.x & 31, ly = threadIdx.x >> 5;  // 32 x 8
    #pragma unroll
    for (int j = 0; j < 4; ++j) {
        int r = r0 + ly + j*8;
        tile[ly + j*8][lx] = (r < R) ? src[(size_t)r*C + c0 + lx] : 0.f;
    }
    __syncthreads();
    #pragma unroll
    for (int j = 0; j < 4; ++j) {
        int c = c0 + ly + j*8;
        dst[(size_t)c*KPAD + r0 + lx] = f2bf(tile[lx][ly + j*8]);
    }
}

// MFMA bf16 GEMM (B^T form): C[M][N] fp32 = A[M][K]bf16 . Bt[N][K]bf16^T + bias
// 128x128 tile, BK=32, 256 threads (4 waves, each 64x64 via 4x4 of 16x16x32 MFMA).
// XOR-swizzled LDS k-slots: 2-way bank aliasing on ds_read_b128 (free).
__global__ __launch_bounds__(256) void mfma_gemm_bt(
    const unsigned short* __restrict__ A, const unsigned short* __restrict__ Bt,
    const float* __restrict__ bias, float* __restrict__ C, int M, int N)
{
    constexpr int K = KPAD;
    __shared__ unsigned short sA[128*32];
    __shared__ unsigned short sB[128*32];
    const int tid = threadIdx.x;
    const int m0 = blockIdx.y * 128, n0 = blockIdx.x * 128;
    const int wave = tid >> 6, lane = tid & 63;
    const int wm = (wave & 1) * 64, wn = (wave >> 1) * 64;
    const int lrow = lane & 15, quad = lane >> 4;

    // staging: lane li covers row r=li/4, lds slot sl=li%4, global k-block q (swizzled)
    const int r0 = tid >> 2, sl = tid & 3;
    const int r1 = r0 + 64;
    const int q0 = sl ^ (r0 & 3) ^ ((r0 >> 2) & 3);
    const int q1 = sl ^ (r1 & 3) ^ ((r1 >> 2) & 3);
    const unsigned short* Ag0 = A + (size_t)min(m0 + r0, M - 1) * K + q0 * 8;
    const unsigned short* Ag1 = A + (size_t)min(m0 + r1, M - 1) * K + q1 * 8;
    const unsigned short* Bg0 = Bt + (size_t)(n0 + r0) * K + q0 * 8;
    const unsigned short* Bg1 = Bt + (size_t)(n0 + r1) * K + q1 * 8;
    unsigned short* sA0 = sA + tid * 8;
    unsigned short* sA1 = sA + (tid + 256) * 8;
    unsigned short* sB0 = sB + tid * 8;
    unsigned short* sB1 = sB + (tid + 256) * 8;

    // fragment read offsets (elements), same swizzle
    int offA[4], offB[4];
    #pragma unroll
    for (int i = 0; i < 4; ++i) {
        int m = wm + i*16 + lrow;
        offA[i] = m*32 + (quad ^ (m & 3) ^ ((m >> 2) & 3)) * 8;
        int n = wn + i*16 + lrow;
        offB[i] = n*32 + (quad ^ (n & 3) ^ ((n >> 2) & 3)) * 8;
    }

    f32x4 acc[4][4] = {};

    for (int k0 = 0; k0 < K; k0 += 32) {
        glds16(Ag0 + k0, sA0);
        glds16(Ag1 + k0, sA1);
        glds16(Bg0 + k0, sB0);
        glds16(Bg1 + k0, sB1);
        __syncthreads();   // drains vmcnt(0) (global_load_lds) + barrier
        bf16x8 af[4], bfr[4];
        #pragma unroll
        for (int i = 0; i < 4; ++i) af[i]  = *(const bf16x8*)&sA[offA[i]];
        #pragma unroll
        for (int i = 0; i < 4; ++i) bfr[i] = *(const bf16x8*)&sB[offB[i]];
        #pragma unroll
        for (int mi = 0; mi < 4; ++mi)
            #pragma unroll
            for (int ni = 0; ni < 4; ++ni)
                acc[mi][ni] = __builtin_amdgcn_mfma_f32_16x16x32_bf16(
                    af[mi], bfr[ni], acc[mi][ni], 0, 0, 0);
        __syncthreads();   // protect LDS before next stage
    }

    // epilogue: C/D layout col=lane&15, row=quad*4+reg
    #pragma unroll
    for (int ni = 0; ni < 4; ++ni) {
        int col = n0 + wn + ni*16 + lrow;
        float bv = bias[col];
        #pragma unroll
        for (int mi = 0; mi < 4; ++mi) {
            int rowb = m0 + wm + mi*16 + quad*4;
            #pragma unroll
            for (int r = 0; r < 4; ++r) {
                int row = rowb + r;
                if (row < M) C[(size_t)row * N + col] = acc[mi][ni][r] + bv;
            }
        }
    }
}

// K5: RMSNorm rows of h2 fp32 [MROWS][1280] -> h2b bf16
__global__ __launch_bounds__(256) void k5_rmsnorm(
    const float* __restrict__ h2, const float* __restrict__ rms_w,
    unsigned short* __restrict__ h2b)
{
    int row = blockIdx.x;
    const float* p = h2 + (size_t)row * H_;
    int tid = threadIdx.x;
    float v[5];
    float s = 0.f;
    #pragma unroll
    for (int i = 0; i < 5; ++i) {
        v[i] = p[tid + i*256];
        s += v[i] * v[i];
    }
    __shared__ float red[256];
    red[tid] = s; __syncthreads();
    for (int off = 128; off > 0; off >>= 1) {
        if (tid < off) red[tid] += red[tid+off];
        __syncthreads();
    }
    float inv = 1.f / sqrtf(red[0] / (float)H_ + 1e-6f);
    unsigned short* dst = h2b + (size_t)row * H_;
    #pragma unroll
    for (int i = 0; i < 5; ++i) {
        int d = tid + i*256;
        dst[d] = f2bf(v[i] * inv * rms_w[d]);
    }
}

extern "C" void kernel_launch(void* const* d_in, const int* in_sizes, int n_in,
                              void* d_out, int out_size, void* d_ws, size_t ws_size,
                              hipStream_t stream) {
    (void)in_sizes; (void)n_in; (void)out_size; (void)ws_size;
    const float* audio      = (const float*)d_in[0];
    const int*   num_tokens = (const int*)d_in[1];
    const float* rms_w      = (const float*)d_in[2];
    const float* cif_w      = (const float*)d_in[3];
    const float* cif_b      = (const float*)d_in[4];
    const float* text_w     = (const float*)d_in[5];
    const float* text_b     = (const float*)d_in[6];

    float* out  = (float*)d_out;                   // fp32 output
    float* pred = out + (size_t)MROWS * OUT_;      // pred_num_tokens tail (8 floats)

    char* ws = (char*)d_ws;
    float* alphas = (float*)(ws + 0);          // 48000 B
    float* w0a    = (float*)(ws + 48000);
    float* w1a    = (float*)(ws + 96000);
    int*   tok0   = (int*)  (ws + 144000);
    int*   tok1   = (int*)  (ws + 192000);
    int*   lo     = (int*)  (ws + 240000);     // 12000 B
    int*   hi     = (int*)  (ws + 252000);     // -> 264000, pad to 264192
    // region R1 (7,680,000 B): h1b (dies after cif GEMM) then h2b
    unsigned short* h1b = (unsigned short*)(ws + 264192);
    unsigned short* h2b = (unsigned short*)(ws + 264192);
    // region R2 (3,276,800 B): cif weight^T bf16 [1280][1280]
    unsigned short* cwt = (unsigned short*)(ws + 7944192);
    // region R3 (15,360,000 B): h2 fp32 (dies after rmsnorm) then text weight^T bf16
    float*          h2  = (float*)         (ws + 11220992);
    unsigned short* twt = (unsigned short*)(ws + 11220992);
    // total ws usage: 26,580,992 B

    k1_alphas<<<B_, 256, 0, stream>>>(audio, num_tokens, alphas, pred, lo, hi);
    k2_scan<<<1, 64, 0, stream>>>(alphas, num_tokens, tok0, w0a, tok1, w1a, lo, hi);
    k3_pool<<<MROWS, 256, 0, stream>>>(audio, tok0, w0a, tok1, w1a, lo, hi, h1b);
    // cif_w [1279][1280] -> cwt [1280][1280] bf16 (k zero-padded)
    transpose_f32_bf16<<<dim3(40, 40), 256, 0, stream>>>(cif_w, cwt, HM1, H_);
    // cif_proj: h2 = h1b[3000x1280] . cwt^T + cif_b
    mfma_gemm_bt<<<dim3(H_/128, (MROWS+127)/128), 256, 0, stream>>>(
        h1b, cwt, cif_b, h2, MROWS, H_);
    k5_rmsnorm<<<MROWS, 256, 0, stream>>>(h2, rms_w, h2b);   // h1b dead, R1 reused
    // text_w [1280][4096] -> twt [4096][1280] bf16  (h2 dead, R3 reused)
    transpose_f32_bf16<<<dim3(128, 40), 256, 0, stream>>>(text_w, twt, H_, OUT_);
    // text_proj: out = h2b[3000x1280] . twt^T + text_b
    mfma_gemm_bt<<<dim3(OUT_/128, (MROWS+127)/128), 256, 0, stream>>>(
        h2b, twt, text_b, out, MROWS, OUT_);
}

// Round 4
// 420.191 us; speedup vs baseline: 2.4366x; 1.0952x over previous
//
#include <hip/hip_runtime.h>
#include <hip/hip_bf16.h>
#include <stdint.h>

// Problem constants (from reference)
#define B_ 8
#define T_ 1500
#define H_ 1280
#define HM1 1279
#define OUT_ 4096
#define MTOK 375
#define MROWS (B_*MTOK)   // 3000
#define KPAD 1280         // shared K for both GEMMs (cif K=1279 zero-padded)

typedef __attribute__((ext_vector_type(8))) short bf16x8;  // 8 bf16 = 4 VGPRs
typedef __attribute__((ext_vector_type(4))) float f32x4;

static __device__ __forceinline__ unsigned short f2bf(float f) {
    unsigned int x = __float_as_uint(f);
    unsigned int r = (x + 0x7fffu + ((x >> 16) & 1u)) >> 16;
    return (unsigned short)r;
}

static __device__ __forceinline__ void glds16(const unsigned short* g, unsigned short* l) {
    __builtin_amdgcn_global_load_lds(
        (const __attribute__((address_space(1))) void*)g,
        (__attribute__((address_space(3))) void*)l, 16, 0, 0);
}

// K1: alphas = sigmoid(audio[:,:,H-1]); pred = sum; alphas *= num_tokens/pred.
__global__ __launch_bounds__(256) void k1_alphas(
    const float* __restrict__ audio, const int* __restrict__ num_tokens,
    float* __restrict__ alphas, float* __restrict__ pred_out,
    int* __restrict__ lo, int* __restrict__ hi)
{
    int b = blockIdx.x;
    int tid = threadIdx.x;
    for (int m = tid; m < MTOK; m += 256) { lo[b*MTOK+m] = T_; hi[b*MTOK+m] = 0; }

    float sig[6];
    float s = 0.f;
    #pragma unroll
    for (int i = 0; i < 6; ++i) {
        int t = tid + i*256;
        sig[i] = 0.f;
        if (t < T_) {
            float x = audio[((size_t)b*T_ + t)*H_ + (H_-1)];
            sig[i] = 1.f / (1.f + expf(-x));
            s += sig[i];
        }
    }
    __shared__ float red[256];
    red[tid] = s; __syncthreads();
    for (int off = 128; off > 0; off >>= 1) {
        if (tid < off) red[tid] += red[tid+off];
        __syncthreads();
    }
    __shared__ float scale_sh;
    if (tid == 0) {
        float pred = red[0];
        pred_out[b] = pred;
        scale_sh = (float)num_tokens[b] / pred;
    }
    __syncthreads();
    float scale = scale_sh;
    #pragma unroll
    for (int i = 0; i < 6; ++i) {
        int t = tid + i*256;
        if (t < T_) alphas[b*T_ + t] = sig[i] * scale;
    }
}

// K2: sequential CIF scan per batch (exact fp32 order as reference).
// Unrolled x4: one ds_read_b128 + vectorized dwordx4 emissions per 4 steps;
// the only serial dependence is the ~3-op integrate chain.
__global__ __launch_bounds__(64) void k2_scan(
    const float* __restrict__ alphas, const int* __restrict__ num_tokens,
    int* __restrict__ tok0, float* __restrict__ w0a,
    int* __restrict__ tok1, float* __restrict__ w1a,
    int* __restrict__ lo, int* __restrict__ hi)
{
    __shared__ float al[B_*T_];  // 48 KB
    {
        float4* d = (float4*)al;
        const float4* s = (const float4*)alphas;
        for (int i = threadIdx.x; i < (B_*T_)/4; i += 64) d[i] = s[i];
    }
    __syncthreads();
    int b = threadIdx.x;
    if (b >= B_) return;
    int nm1 = num_tokens[b] - 1;
    float integrate = 0.f;
    int tok = 0;
    lo[b*MTOK] = 0;
    const float* alb = &al[b*T_];
    const int base = b*T_;
    for (int t = 0; t < T_; t += 4) {
        float4 a4 = *(const float4*)(alb + t);   // ds_read_b128, hoisted ahead
        int   t0v[4]; float w0v[4]; int t1v[4]; float w1v[4];
        float av[4] = {a4.x, a4.y, a4.z, a4.w};
        #pragma unroll
        for (int j = 0; j < 4; ++j) {
            float alpha = av[j];
            float need  = 1.f - integrate;
            float s     = integrate + alpha;
            bool ready  = (s >= 1.f);
            float a_int = ready ? need : alpha;
            float n_int = ready ? (s - 1.f) : s;
            float rem   = alpha - a_int;
            int ntok    = ready ? min(tok + 1, nm1) : tok;
            t0v[j] = tok;  w0v[j] = a_int;
            t1v[j] = ntok; w1v[j] = (t + j < T_-1) ? rem : 0.f;
            if (ntok != tok) {             // rare (~25%): range bookkeeping
                hi[b*MTOK + tok]  = t + j + 1;
                lo[b*MTOK + ntok] = t + j;
            }
            integrate = n_int; tok = ntok;
        }
        *(int4*)  (tok0 + base + t) = *(int4*)t0v;
        *(float4*)(w0a  + base + t) = *(float4*)w0v;
        *(int4*)  (tok1 + base + t) = *(int4*)t1v;
        *(float4*)(w1a  + base + t) = *(float4*)w1v;
    }
    hi[b*MTOK + tok] = T_;
}

// K3: sparse pooling -> h1b bf16 [MROWS][KPAD], col 1279 = 0
__global__ __launch_bounds__(256) void k3_pool(
    const float* __restrict__ audio,
    const int* __restrict__ tok0, const float* __restrict__ w0a,
    const int* __restrict__ tok1, const float* __restrict__ w1a,
    const int* __restrict__ lo, const int* __restrict__ hi,
    unsigned short* __restrict__ h1b)
{
    int bm = blockIdx.x;
    int b = bm / MTOK, m = bm % MTOK;
    int l = lo[bm], h = hi[bm];
    int tid = threadIdx.x;
    float acc[5] = {0.f,0.f,0.f,0.f,0.f};
    for (int t = l; t < h; ++t) {
        int i0 = b*T_ + t;
        float w = 0.f;
        if (tok0[i0] == m) w += w0a[i0];
        if (tok1[i0] == m) w += w1a[i0];
        if (w != 0.f) {
            const float* row = audio + (size_t)i0 * H_;
            #pragma unroll
            for (int i = 0; i < 5; ++i) {
                int d = tid + i*256;
                if (d < HM1) acc[i] += w * row[d];
            }
        }
    }
    unsigned short* dst = h1b + (size_t)bm * KPAD;
    #pragma unroll
    for (int i = 0; i < 5; ++i) {
        int d = tid + i*256;
        dst[d] = (d < HM1) ? f2bf(acc[i]) : (unsigned short)0;
    }
}

// Transpose+convert: dst[c][r] (bf16, r padded to KPAD with 0) = src[r][c] (fp32)
__global__ __launch_bounds__(256) void transpose_f32_bf16(
    const float* __restrict__ src, unsigned short* __restrict__ dst, int R, int C)
{
    __shared__ float tile[32][33];
    int c0 = blockIdx.x * 32, r0 = blockIdx.y * 32;
    int lx = threadIdx.x & 31, ly = threadIdx.x >> 5;  // 32 x 8
    #pragma unroll
    for (int j = 0; j < 4; ++j) {
        int r = r0 + ly + j*8;
        tile[ly + j*8][lx] = (r < R) ? src[(size_t)r*C + c0 + lx] : 0.f;
    }
    __syncthreads();
    #pragma unroll
    for (int j = 0; j < 4; ++j) {
        int c = c0 + ly + j*8;
        dst[(size_t)c*KPAD + r0 + lx] = f2bf(tile[lx][ly + j*8]);
    }
}

// MFMA bf16 GEMM (B^T form): C[M][N] fp32 = A[M][K]bf16 . Bt[N][K]bf16^T + bias
// 128x128 tile, BK=32, 256 threads (4 waves, each 64x64 via 4x4 of 16x16x32 MFMA).
// XOR-swizzled LDS k-slots: 2-way bank aliasing on ds_read_b128 (free).
__global__ __launch_bounds__(256) void mfma_gemm_bt(
    const unsigned short* __restrict__ A, const unsigned short* __restrict__ Bt,
    const float* __restrict__ bias, float* __restrict__ C, int M, int N)
{
    constexpr int K = KPAD;
    __shared__ unsigned short sA[128*32];
    __shared__ unsigned short sB[128*32];
    const int tid = threadIdx.x;
    const int m0 = blockIdx.y * 128, n0 = blockIdx.x * 128;
    const int wave = tid >> 6, lane = tid & 63;
    const int wm = (wave & 1) * 64, wn = (wave >> 1) * 64;
    const int lrow = lane & 15, quad = lane >> 4;

    const int r0 = tid >> 2, sl = tid & 3;
    const int r1 = r0 + 64;
    const int q0 = sl ^ (r0 & 3) ^ ((r0 >> 2) & 3);
    const int q1 = sl ^ (r1 & 3) ^ ((r1 >> 2) & 3);
    const unsigned short* Ag0 = A + (size_t)min(m0 + r0, M - 1) * K + q0 * 8;
    const unsigned short* Ag1 = A + (size_t)min(m0 + r1, M - 1) * K + q1 * 8;
    const unsigned short* Bg0 = Bt + (size_t)(n0 + r0) * K + q0 * 8;
    const unsigned short* Bg1 = Bt + (size_t)(n0 + r1) * K + q1 * 8;
    unsigned short* sA0 = sA + tid * 8;
    unsigned short* sA1 = sA + (tid + 256) * 8;
    unsigned short* sB0 = sB + tid * 8;
    unsigned short* sB1 = sB + (tid + 256) * 8;

    int offA[4], offB[4];
    #pragma unroll
    for (int i = 0; i < 4; ++i) {
        int m = wm + i*16 + lrow;
        offA[i] = m*32 + (quad ^ (m & 3) ^ ((m >> 2) & 3)) * 8;
        int n = wn + i*16 + lrow;
        offB[i] = n*32 + (quad ^ (n & 3) ^ ((n >> 2) & 3)) * 8;
    }

    f32x4 acc[4][4] = {};

    for (int k0 = 0; k0 < K; k0 += 32) {
        glds16(Ag0 + k0, sA0);
        glds16(Ag1 + k0, sA1);
        glds16(Bg0 + k0, sB0);
        glds16(Bg1 + k0, sB1);
        __syncthreads();
        bf16x8 af[4], bfr[4];
        #pragma unroll
        for (int i = 0; i < 4; ++i) af[i]  = *(const bf16x8*)&sA[offA[i]];
        #pragma unroll
        for (int i = 0; i < 4; ++i) bfr[i] = *(const bf16x8*)&sB[offB[i]];
        #pragma unroll
        for (int mi = 0; mi < 4; ++mi)
            #pragma unroll
            for (int ni = 0; ni < 4; ++ni)
                acc[mi][ni] = __builtin_amdgcn_mfma_f32_16x16x32_bf16(
                    af[mi], bfr[ni], acc[mi][ni], 0, 0, 0);
        __syncthreads();
    }

    #pragma unroll
    for (int ni = 0; ni < 4; ++ni) {
        int col = n0 + wn + ni*16 + lrow;
        float bv = bias[col];
        #pragma unroll
        for (int mi = 0; mi < 4; ++mi) {
            int rowb = m0 + wm + mi*16 + quad*4;
            #pragma unroll
            for (int r = 0; r < 4; ++r) {
                int row = rowb + r;
                if (row < M) C[(size_t)row * N + col] = acc[mi][ni][r] + bv;
            }
        }
    }
}

// K5: RMSNorm rows of h2 fp32 [MROWS][1280] -> h2b bf16
__global__ __launch_bounds__(256) void k5_rmsnorm(
    const float* __restrict__ h2, const float* __restrict__ rms_w,
    unsigned short* __restrict__ h2b)
{
    int row = blockIdx.x;
    const float* p = h2 + (size_t)row * H_;
    int tid = threadIdx.x;
    float v[5];
    float s = 0.f;
    #pragma unroll
    for (int i = 0; i < 5; ++i) {
        v[i] = p[tid + i*256];
        s += v[i] * v[i];
    }
    __shared__ float red[256];
    red[tid] = s; __syncthreads();
    for (int off = 128; off > 0; off >>= 1) {
        if (tid < off) red[tid] += red[tid+off];
        __syncthreads();
    }
    float inv = 1.f / sqrtf(red[0] / (float)H_ + 1e-6f);
    unsigned short* dst = h2b + (size_t)row * H_;
    #pragma unroll
    for (int i = 0; i < 5; ++i) {
        int d = tid + i*256;
        dst[d] = f2bf(v[i] * inv * rms_w[d]);
    }
}

extern "C" void kernel_launch(void* const* d_in, const int* in_sizes, int n_in,
                              void* d_out, int out_size, void* d_ws, size_t ws_size,
                              hipStream_t stream) {
    (void)in_sizes; (void)n_in; (void)out_size; (void)ws_size;
    const float* audio      = (const float*)d_in[0];
    const int*   num_tokens = (const int*)d_in[1];
    const float* rms_w      = (const float*)d_in[2];
    const float* cif_w      = (const float*)d_in[3];
    const float* cif_b      = (const float*)d_in[4];
    const float* text_w     = (const float*)d_in[5];
    const float* text_b     = (const float*)d_in[6];

    float* out  = (float*)d_out;                   // fp32 output
    float* pred = out + (size_t)MROWS * OUT_;      // pred_num_tokens tail (8 floats)

    char* ws = (char*)d_ws;
    float* alphas = (float*)(ws + 0);          // 48000 B
    float* w0a    = (float*)(ws + 48000);
    float* w1a    = (float*)(ws + 96000);
    int*   tok0   = (int*)  (ws + 144000);
    int*   tok1   = (int*)  (ws + 192000);
    int*   lo     = (int*)  (ws + 240000);     // 12000 B
    int*   hi     = (int*)  (ws + 252000);     // -> 264000, pad to 264192
    // region R1 (7,680,000 B): h1b (dies after cif GEMM) then h2b
    unsigned short* h1b = (unsigned short*)(ws + 264192);
    unsigned short* h2b = (unsigned short*)(ws + 264192);
    // region R2 (3,276,800 B): cif weight^T bf16 [1280][1280]
    unsigned short* cwt = (unsigned short*)(ws + 7944192);
    // region R3 (15,360,000 B): h2 fp32 (dies after rmsnorm) then text weight^T bf16
    float*          h2  = (float*)         (ws + 11220992);
    unsigned short* twt = (unsigned short*)(ws + 11220992);
    // total ws usage: 26,580,992 B

    k1_alphas<<<B_, 256, 0, stream>>>(audio, num_tokens, alphas, pred, lo, hi);
    k2_scan<<<1, 64, 0, stream>>>(alphas, num_tokens, tok0, w0a, tok1, w1a, lo, hi);
    k3_pool<<<MROWS, 256, 0, stream>>>(audio, tok0, w0a, tok1, w1a, lo, hi, h1b);
    // cif_w [1279][1280] -> cwt [1280][1280] bf16 (k zero-padded)
    transpose_f32_bf16<<<dim3(40, 40), 256, 0, stream>>>(cif_w, cwt, HM1, H_);
    // cif_proj: h2 = h1b[3000x1280] . cwt^T + cif_b
    mfma_gemm_bt<<<dim3(H_/128, (MROWS+127)/128), 256, 0, stream>>>(
        h1b, cwt, cif_b, h2, MROWS, H_);
    k5_rmsnorm<<<MROWS, 256, 0, stream>>>(h2, rms_w, h2b);   // h1b dead, R1 reused
    // text_w [1280][4096] -> twt [4096][1280] bf16  (h2 dead, R3 reused)
    transpose_f32_bf16<<<dim3(128, 40), 256, 0, stream>>>(text_w, twt, H_, OUT_);
    // text_proj: out = h2b[3000x1280] . twt^T + text_b
    mfma_gemm_bt<<<dim3(OUT_/128, (MROWS+127)/128), 256, 0, stream>>>(
        h2b, twt, text_b, out, MROWS, OUT_);
}

// Round 6
// 306.599 us; speedup vs baseline: 3.3394x; 1.3705x over previous
//
#include <hip/hip_runtime.h>
#include <hip/hip_bf16.h>
#include <stdint.h>

// Problem constants (from reference)
#define B_ 8
#define T_ 1500
#define H_ 1280
#define HM1 1279
#define OUT_ 4096
#define MTOK 375
#define MROWS (B_*MTOK)   // 3000
#define KPAD 1280         // shared K for both GEMMs (cif K=1279 zero-padded)

typedef __attribute__((ext_vector_type(8))) short bf16x8;  // 8 bf16 = 4 VGPRs
typedef __attribute__((ext_vector_type(4))) float f32x4;

static __device__ __forceinline__ unsigned short f2bf(float f) {
    unsigned int x = __float_as_uint(f);
    unsigned int r = (x + 0x7fffu + ((x >> 16) & 1u)) >> 16;
    return (unsigned short)r;
}

static __device__ __forceinline__ void glds16(const unsigned short* g, unsigned short* l) {
    __builtin_amdgcn_global_load_lds(
        (const __attribute__((address_space(1))) void*)g,
        (__attribute__((address_space(3))) void*)l, 16, 0, 0);
}

// Fused: sigmoid+pred+scale -> serial carry scan (LDS-only emissions)
// -> parallel post-pass (fires, prefix-sum token indices, w0/w1, lo/hi).
// One block per batch.
__global__ __launch_bounds__(256) void k_alpha_scan(
    const float* __restrict__ audio, const int* __restrict__ num_tokens,
    float* __restrict__ pred_out,
    int* __restrict__ tok0, float* __restrict__ w0a,
    int* __restrict__ tok1, float* __restrict__ w1a,
    int* __restrict__ lo, int* __restrict__ hi)
{
    const int b = blockIdx.x;
    const int tid = threadIdx.x;
    __shared__ float al[T_];     // alphas (post-scale)
    __shared__ float ip[T_];     // integrate BEFORE adding al[t] (exact carry)
    __shared__ float red[256];
    __shared__ int   redI[256];
    __shared__ float scale_sh;

    // ---- phase 1: sigmoid + pred + scale ----
    float sig[6];
    float s = 0.f;
    #pragma unroll
    for (int i = 0; i < 6; ++i) {
        int t = tid + i*256;
        sig[i] = 0.f;
        if (t < T_) {
            float x = audio[((size_t)b*T_ + t)*H_ + (H_-1)];
            sig[i] = 1.f / (1.f + expf(-x));
            s += sig[i];
        }
    }
    red[tid] = s; __syncthreads();
    for (int off = 128; off > 0; off >>= 1) {
        if (tid < off) red[tid] += red[tid+off];
        __syncthreads();
    }
    if (tid == 0) {
        float pred = red[0];
        pred_out[b] = pred;
        scale_sh = (float)num_tokens[b] / pred;
    }
    __syncthreads();
    float scale = scale_sh;
    #pragma unroll
    for (int i = 0; i < 6; ++i) {
        int t = tid + i*256;
        if (t < T_) al[t] = sig[i] * scale;
    }
    // init lo/hi for this batch
    for (int m = tid; m < MTOK; m += 256) {
        lo[b*MTOK+m] = T_; hi[b*MTOK+m] = 0;
    }
    if (tid == 0) lo[b*MTOK] = 0;
    __syncthreads();

    // ---- phase 2: serial carry chain (lane 0), LDS-only emissions ----
    if (tid == 0) {
        float integ = 0.f;
        float4 cur = *(const float4*)&al[0];
        for (int t = 0; t < T_; t += 4) {
            float4 nxt = (t + 4 < T_) ? *(const float4*)&al[t+4]
                                      : make_float4(0.f,0.f,0.f,0.f);
            float av[4] = {cur.x, cur.y, cur.z, cur.w};
            float ipv[4];
            #pragma unroll
            for (int j = 0; j < 4; ++j) {
                ipv[j] = integ;
                float sx = integ + av[j];
                integ = (sx >= 1.f) ? (sx - 1.f) : sx;
            }
            *(float4*)&ip[t] = *(float4*)ipv;   // ds_write_b128
            cur = nxt;
        }
    }
    __syncthreads();

    // ---- phase 3: parallel post-pass; thread covers 6 contiguous t ----
    const int t0 = tid * 6;                    // 250 threads cover 1500
    const int nm1 = num_tokens[b] - 1;
    int fires[6];
    int cnt = 0;
    if (t0 < T_) {
        #pragma unroll
        for (int j = 0; j < 6; ++j) {
            int t = t0 + j;
            float sx = ip[t] + al[t];          // same fp32 add as serial scan
            fires[j] = (sx >= 1.f) ? 1 : 0;
            cnt += fires[j];
        }
    }
    redI[tid] = cnt; __syncthreads();
    // Kogge-Stone inclusive scan over 256
    #pragma unroll
    for (int off = 1; off < 256; off <<= 1) {
        int v = redI[tid];
        if (tid >= off) v += redI[tid - off];
        __syncthreads();
        redI[tid] = v;
        __syncthreads();
    }
    if (t0 < T_) {
        int F = redI[tid] - cnt;               // exclusive prefix (fires before t0)
        const int base = b*T_;
        #pragma unroll
        for (int j = 0; j < 6; ++j) {
            int t = t0 + j;
            float a = al[t], ipv = ip[t];
            int fire = fires[j];
            F += fire;                          // inclusive fire count at t
            int tk1 = min(F, nm1);
            int tk0 = min(F - fire, nm1);
            float w0 = fire ? (1.f - ipv) : a;  // alpha_needed vs alpha (exact)
            float w1 = (t < T_-1) ? (a - w0) : 0.f;
            tok0[base+t] = tk0;  w0a[base+t] = w0;
            tok1[base+t] = tk1;  w1a[base+t] = w1;
            if (tk1 != tk0) {                   // fire transition bookkeeping
                hi[b*MTOK + tk0] = t + 1;
                lo[b*MTOK + tk1] = t;
            }
            if (t == T_-1) hi[b*MTOK + tk1] = T_;
        }
    }
}

// K3: sparse pooling -> h1b bf16 [MROWS][KPAD], col 1279 = 0
__global__ __launch_bounds__(256) void k3_pool(
    const float* __restrict__ audio,
    const int* __restrict__ tok0, const float* __restrict__ w0a,
    const int* __restrict__ tok1, const float* __restrict__ w1a,
    const int* __restrict__ lo, const int* __restrict__ hi,
    unsigned short* __restrict__ h1b)
{
    int bm = blockIdx.x;
    int b = bm / MTOK, m = bm % MTOK;
    int l = lo[bm], h = hi[bm];
    int tid = threadIdx.x;
    float acc[5] = {0.f,0.f,0.f,0.f,0.f};
    for (int t = l; t < h; ++t) {
        int i0 = b*T_ + t;
        float w = 0.f;
        if (tok0[i0] == m) w += w0a[i0];
        if (tok1[i0] == m) w += w1a[i0];
        if (w != 0.f) {
            const float* row = audio + (size_t)i0 * H_;
            #pragma unroll
            for (int i = 0; i < 5; ++i) {
                int d = tid + i*256;
                if (d < HM1) acc[i] += w * row[d];
            }
        }
    }
    unsigned short* dst = h1b + (size_t)bm * KPAD;
    #pragma unroll
    for (int i = 0; i < 5; ++i) {
        int d = tid + i*256;
        dst[d] = (d < HM1) ? f2bf(acc[i]) : (unsigned short)0;
    }
}

// Transpose+convert: dst[c][r] (bf16, r padded to KPAD with 0) = src[r][c] (fp32)
__global__ __launch_bounds__(256) void transpose_f32_bf16(
    const float* __restrict__ src, unsigned short* __restrict__ dst, int R, int C)
{
    __shared__ float tile[32][33];
    int c0 = blockIdx.x * 32, r0 = blockIdx.y * 32;
    int lx = threadIdx.x & 31, ly = threadIdx.x >> 5;  // 32 x 8
    #pragma unroll
    for (int j = 0; j < 4; ++j) {
        int r = r0 + ly + j*8;
        tile[ly + j*8][lx] = (r < R) ? src[(size_t)r*C + c0 + lx] : 0.f;
    }
    __syncthreads();
    #pragma unroll
    for (int j = 0; j < 4; ++j) {
        int c = c0 + ly + j*8;
        dst[(size_t)c*KPAD + r0 + lx] = f2bf(tile[lx][ly + j*8]);
    }
}

// MFMA bf16 GEMM (B^T form): C[M][N] fp32 = A[M][K]bf16 . Bt[N][K]bf16^T + bias
// 128x128 tile, BK=32, 256 threads (4 waves). XOR-swizzled LDS k-slots.
__global__ __launch_bounds__(256) void mfma_gemm_bt(
    const unsigned short* __restrict__ A, const unsigned short* __restrict__ Bt,
    const float* __restrict__ bias, float* __restrict__ C, int M, int N)
{
    constexpr int K = KPAD;
    __shared__ unsigned short sA[128*32];
    __shared__ unsigned short sB[128*32];
    const int tid = threadIdx.x;
    const int m0 = blockIdx.y * 128, n0 = blockIdx.x * 128;
    const int wave = tid >> 6, lane = tid & 63;
    const int wm = (wave & 1) * 64, wn = (wave >> 1) * 64;
    const int lrow = lane & 15, quad = lane >> 4;

    const int r0 = tid >> 2, sl = tid & 3;
    const int r1 = r0 + 64;
    const int q0 = sl ^ (r0 & 3) ^ ((r0 >> 2) & 3);
    const int q1 = sl ^ (r1 & 3) ^ ((r1 >> 2) & 3);
    const unsigned short* Ag0 = A + (size_t)min(m0 + r0, M - 1) * K + q0 * 8;
    const unsigned short* Ag1 = A + (size_t)min(m0 + r1, M - 1) * K + q1 * 8;
    const unsigned short* Bg0 = Bt + (size_t)(n0 + r0) * K + q0 * 8;
    const unsigned short* Bg1 = Bt + (size_t)(n0 + r1) * K + q1 * 8;
    unsigned short* sA0 = sA + tid * 8;
    unsigned short* sA1 = sA + (tid + 256) * 8;
    unsigned short* sB0 = sB + tid * 8;
    unsigned short* sB1 = sB + (tid + 256) * 8;

    int offA[4], offB[4];
    #pragma unroll
    for (int i = 0; i < 4; ++i) {
        int m = wm + i*16 + lrow;
        offA[i] = m*32 + (quad ^ (m & 3) ^ ((m >> 2) & 3)) * 8;
        int n = wn + i*16 + lrow;
        offB[i] = n*32 + (quad ^ (n & 3) ^ ((n >> 2) & 3)) * 8;
    }

    f32x4 acc[4][4] = {};

    for (int k0 = 0; k0 < K; k0 += 32) {
        glds16(Ag0 + k0, sA0);
        glds16(Ag1 + k0, sA1);
        glds16(Bg0 + k0, sB0);
        glds16(Bg1 + k0, sB1);
        __syncthreads();
        bf16x8 af[4], bfr[4];
        #pragma unroll
        for (int i = 0; i < 4; ++i) af[i]  = *(const bf16x8*)&sA[offA[i]];
        #pragma unroll
        for (int i = 0; i < 4; ++i) bfr[i] = *(const bf16x8*)&sB[offB[i]];
        #pragma unroll
        for (int mi = 0; mi < 4; ++mi)
            #pragma unroll
            for (int ni = 0; ni < 4; ++ni)
                acc[mi][ni] = __builtin_amdgcn_mfma_f32_16x16x32_bf16(
                    af[mi], bfr[ni], acc[mi][ni], 0, 0, 0);
        __syncthreads();
    }

    #pragma unroll
    for (int ni = 0; ni < 4; ++ni) {
        int col = n0 + wn + ni*16 + lrow;
        float bv = bias[col];
        #pragma unroll
        for (int mi = 0; mi < 4; ++mi) {
            int rowb = m0 + wm + mi*16 + quad*4;
            #pragma unroll
            for (int r = 0; r < 4; ++r) {
                int row = rowb + r;
                if (row < M) C[(size_t)row * N + col] = acc[mi][ni][r] + bv;
            }
        }
    }
}

// K5: RMSNorm rows of h2 fp32 [MROWS][1280] -> h2b bf16
__global__ __launch_bounds__(256) void k5_rmsnorm(
    const float* __restrict__ h2, const float* __restrict__ rms_w,
    unsigned short* __restrict__ h2b)
{
    int row = blockIdx.x;
    const float* p = h2 + (size_t)row * H_;
    int tid = threadIdx.x;
    float v[5];
    float s = 0.f;
    #pragma unroll
    for (int i = 0; i < 5; ++i) {
        v[i] = p[tid + i*256];
        s += v[i] * v[i];
    }
    __shared__ float red[256];
    red[tid] = s; __syncthreads();
    for (int off = 128; off > 0; off >>= 1) {
        if (tid < off) red[tid] += red[tid+off];
        __syncthreads();
    }
    float inv = 1.f / sqrtf(red[0] / (float)H_ + 1e-6f);
    unsigned short* dst = h2b + (size_t)row * H_;
    #pragma unroll
    for (int i = 0; i < 5; ++i) {
        int d = tid + i*256;
        dst[d] = f2bf(v[i] * inv * rms_w[d]);
    }
}

extern "C" void kernel_launch(void* const* d_in, const int* in_sizes, int n_in,
                              void* d_out, int out_size, void* d_ws, size_t ws_size,
                              hipStream_t stream) {
    (void)in_sizes; (void)n_in; (void)out_size; (void)ws_size;
    const float* audio      = (const float*)d_in[0];
    const int*   num_tokens = (const int*)d_in[1];
    const float* rms_w      = (const float*)d_in[2];
    const float* cif_w      = (const float*)d_in[3];
    const float* cif_b      = (const float*)d_in[4];
    const float* text_w     = (const float*)d_in[5];
    const float* text_b     = (const float*)d_in[6];

    float* out  = (float*)d_out;                   // fp32 output
    float* pred = out + (size_t)MROWS * OUT_;      // pred_num_tokens tail (8 floats)

    char* ws = (char*)d_ws;
    float* w0a    = (float*)(ws + 48000);
    float* w1a    = (float*)(ws + 96000);
    int*   tok0   = (int*)  (ws + 144000);
    int*   tok1   = (int*)  (ws + 192000);
    int*   lo     = (int*)  (ws + 240000);     // 12000 B
    int*   hi     = (int*)  (ws + 252000);     // -> 264000, pad to 264192
    // region R1 (7,680,000 B): h1b (dies after cif GEMM) then h2b
    unsigned short* h1b = (unsigned short*)(ws + 264192);
    unsigned short* h2b = (unsigned short*)(ws + 264192);
    // region R2 (3,276,800 B): cif weight^T bf16 [1280][1280]  — private, safe early
    unsigned short* cwt = (unsigned short*)(ws + 7944192);
    // region R3 (15,360,000 B): h2 fp32, then (AFTER rmsnorm) text weight^T bf16.
    // LIFETIME ORDER MATTERS: twt must be written only after h2 is dead —
    // round-5's NaN came from writing twt first and clobbering it with h2.
    float*          h2  = (float*)         (ws + 11220992);
    unsigned short* twt = (unsigned short*)(ws + 11220992);
    // total ws usage: 26,580,992 B

    // fused sigmoid + CIF scan + post-pass
    k_alpha_scan<<<B_, 256, 0, stream>>>(audio, num_tokens, pred,
                                         tok0, w0a, tok1, w1a, lo, hi);
    k3_pool<<<MROWS, 256, 0, stream>>>(audio, tok0, w0a, tok1, w1a, lo, hi, h1b);
    // cif_w [1279][1280] -> cwt [1280][1280] bf16 (k zero-padded)
    transpose_f32_bf16<<<dim3(40, 40), 256, 0, stream>>>(cif_w, cwt, HM1, H_);
    // cif_proj: h2 = h1b[3000x1280] . cwt^T + cif_b
    mfma_gemm_bt<<<dim3(H_/128, (MROWS+127)/128), 256, 0, stream>>>(
        h1b, cwt, cif_b, h2, MROWS, H_);
    k5_rmsnorm<<<MROWS, 256, 0, stream>>>(h2, rms_w, h2b);   // h1b dead, R1 reused
    // text_w [1280][4096] -> twt [4096][1280] bf16  (h2 dead, R3 reused)
    transpose_f32_bf16<<<dim3(128, 40), 256, 0, stream>>>(text_w, twt, H_, OUT_);
    // text_proj: out = h2b[3000x1280] . twt^T + text_b
    mfma_gemm_bt<<<dim3(OUT_/128, (MROWS+127)/128), 256, 0, stream>>>(
        h2b, twt, text_b, out, MROWS, OUT_);
}

// Round 7
// 288.904 us; speedup vs baseline: 3.5439x; 1.0612x over previous
//
#include <hip/hip_runtime.h>
#include <hip/hip_bf16.h>
#include <stdint.h>

// Problem constants (from reference)
#define B_ 8
#define T_ 1500
#define H_ 1280
#define HM1 1279
#define OUT_ 4096
#define MTOK 375
#define MROWS (B_*MTOK)   // 3000
#define KPAD 1280         // shared K for both GEMMs (cif K=1279 zero-padded)

typedef __attribute__((ext_vector_type(8))) short bf16x8;  // 8 bf16 = 4 VGPRs
typedef __attribute__((ext_vector_type(4))) float f32x4;

static __device__ __forceinline__ unsigned short f2bf(float f) {
    unsigned int x = __float_as_uint(f);
    unsigned int r = (x + 0x7fffu + ((x >> 16) & 1u)) >> 16;
    return (unsigned short)r;
}
static __device__ __forceinline__ float bf2f(unsigned short u) {
    return __uint_as_float(((unsigned int)u) << 16);
}
static __device__ __forceinline__ void glds16(const unsigned short* g, unsigned short* l) {
    __builtin_amdgcn_global_load_lds(
        (const __attribute__((address_space(1))) void*)g,
        (__attribute__((address_space(3))) void*)l, 16, 0, 0);
}

// Front kernel: blocks 0..7 run the fused sigmoid+scan+post-pass (one per batch);
// blocks 8.. run both weight transposes (fills the GPU during the serial scan).
__global__ __launch_bounds__(256) void k_front(
    const float* __restrict__ audio, const int* __restrict__ num_tokens,
    float* __restrict__ pred_out,
    int* __restrict__ tok0, float* __restrict__ w0a,
    int* __restrict__ tok1, float* __restrict__ w1a,
    int* __restrict__ lo, int* __restrict__ hi,
    const float* __restrict__ cif_w, const float* __restrict__ text_w,
    unsigned short* __restrict__ cwt, unsigned short* __restrict__ twt)
{
    __shared__ float smem[3514];   // union: scan(3513 floats) / transpose tile(32x33)
    const int tid = threadIdx.x;

    if (blockIdx.x < B_) {
        // ================= CIF scan branch =================
        const int b = blockIdx.x;
        float* al = smem;              // [1500]
        float* ip = smem + 1500;       // [1500]
        float* red = smem + 3000;      // [256]
        int*   redI = (int*)(smem + 3256);  // [256]
        float* scale_sh = smem + 3512;

        // phase 1: sigmoid + pred + scale
        float sig[6];
        float s = 0.f;
        #pragma unroll
        for (int i = 0; i < 6; ++i) {
            int t = tid + i*256;
            sig[i] = 0.f;
            if (t < T_) {
                float x = audio[((size_t)b*T_ + t)*H_ + (H_-1)];
                sig[i] = 1.f / (1.f + expf(-x));
                s += sig[i];
            }
        }
        red[tid] = s; __syncthreads();
        for (int off = 128; off > 0; off >>= 1) {
            if (tid < off) red[tid] += red[tid+off];
            __syncthreads();
        }
        if (tid == 0) {
            float pred = red[0];
            pred_out[b] = pred;
            *scale_sh = (float)num_tokens[b] / pred;
        }
        __syncthreads();
        float scale = *scale_sh;
        #pragma unroll
        for (int i = 0; i < 6; ++i) {
            int t = tid + i*256;
            if (t < T_) al[t] = sig[i] * scale;
        }
        for (int m = tid; m < MTOK; m += 256) {
            lo[b*MTOK+m] = T_; hi[b*MTOK+m] = 0;
        }
        if (tid == 0) lo[b*MTOK] = 0;
        __syncthreads();

        // phase 2: serial carry chain (lane 0), LDS-only emissions
        if (tid == 0) {
            float integ = 0.f;
            float4 cur = *(const float4*)&al[0];
            for (int t = 0; t < T_; t += 4) {
                float4 nxt = (t + 4 < T_) ? *(const float4*)&al[t+4]
                                          : make_float4(0.f,0.f,0.f,0.f);
                float av[4] = {cur.x, cur.y, cur.z, cur.w};
                float ipv[4];
                #pragma unroll
                for (int j = 0; j < 4; ++j) {
                    ipv[j] = integ;
                    float sx = integ + av[j];
                    integ = (sx >= 1.f) ? (sx - 1.f) : sx;
                }
                *(float4*)&ip[t] = *(float4*)ipv;
                cur = nxt;
            }
        }
        __syncthreads();

        // phase 3: parallel post-pass
        const int t0 = tid * 6;
        const int nm1 = num_tokens[b] - 1;
        int fires[6];
        int cnt = 0;
        if (t0 < T_) {
            #pragma unroll
            for (int j = 0; j < 6; ++j) {
                int t = t0 + j;
                float sx = ip[t] + al[t];      // same fp32 add as serial scan
                fires[j] = (sx >= 1.f) ? 1 : 0;
                cnt += fires[j];
            }
        }
        redI[tid] = cnt; __syncthreads();
        #pragma unroll
        for (int off = 1; off < 256; off <<= 1) {
            int v = redI[tid];
            if (tid >= off) v += redI[tid - off];
            __syncthreads();
            redI[tid] = v;
            __syncthreads();
        }
        if (t0 < T_) {
            int F = redI[tid] - cnt;
            const int base = b*T_;
            #pragma unroll
            for (int j = 0; j < 6; ++j) {
                int t = t0 + j;
                float a = al[t], ipv = ip[t];
                int fire = fires[j];
                F += fire;
                int tk1 = min(F, nm1);
                int tk0 = min(F - fire, nm1);
                float w0 = fire ? (1.f - ipv) : a;
                float w1 = (t < T_-1) ? (a - w0) : 0.f;
                tok0[base+t] = tk0;  w0a[base+t] = w0;
                tok1[base+t] = tk1;  w1a[base+t] = w1;
                if (tk1 != tk0) {
                    hi[b*MTOK + tk0] = t + 1;
                    lo[b*MTOK + tk1] = t;
                }
                if (t == T_-1) hi[b*MTOK + tk1] = T_;
            }
        }
    } else {
        // ================= transpose branch =================
        float (*tile)[33] = (float(*)[33])smem;
        int blk = blockIdx.x - B_;
        const float* src; unsigned short* dst; int R, C, bx, by;
        if (blk < 1600) { src = cif_w;  dst = cwt; R = HM1; C = H_;   bx = blk % 40;  by = blk / 40; }
        else { blk -= 1600; src = text_w; dst = twt; R = H_;  C = OUT_; bx = blk % 128; by = blk / 128; }
        int c0 = bx * 32, r0 = by * 32;
        int lx = tid & 31, ly = tid >> 5;  // 32 x 8
        #pragma unroll
        for (int j = 0; j < 4; ++j) {
            int r = r0 + ly + j*8;
            tile[ly + j*8][lx] = (r < R) ? src[(size_t)r*C + c0 + lx] : 0.f;
        }
        __syncthreads();
        #pragma unroll
        for (int j = 0; j < 4; ++j) {
            int c = c0 + ly + j*8;
            dst[(size_t)c*KPAD + r0 + lx] = f2bf(tile[lx][ly + j*8]);
        }
    }
}

// K3: sparse pooling -> h1b bf16 [MROWS][KPAD], col 1279 = 0
__global__ __launch_bounds__(256) void k3_pool(
    const float* __restrict__ audio,
    const int* __restrict__ tok0, const float* __restrict__ w0a,
    const int* __restrict__ tok1, const float* __restrict__ w1a,
    const int* __restrict__ lo, const int* __restrict__ hi,
    unsigned short* __restrict__ h1b)
{
    int bm = blockIdx.x;
    int b = bm / MTOK, m = bm % MTOK;
    int l = lo[bm], h = hi[bm];
    int tid = threadIdx.x;
    float acc[5] = {0.f,0.f,0.f,0.f,0.f};
    for (int t = l; t < h; ++t) {
        int i0 = b*T_ + t;
        float w = 0.f;
        if (tok0[i0] == m) w += w0a[i0];
        if (tok1[i0] == m) w += w1a[i0];
        if (w != 0.f) {
            const float* row = audio + (size_t)i0 * H_;
            #pragma unroll
            for (int i = 0; i < 5; ++i) {
                int d = tid + i*256;
                if (d < HM1) acc[i] += w * row[d];
            }
        }
    }
    unsigned short* dst = h1b + (size_t)bm * KPAD;
    #pragma unroll
    for (int i = 0; i < 5; ++i) {
        int d = tid + i*256;
        dst[d] = (d < HM1) ? f2bf(acc[i]) : (unsigned short)0;
    }
}

// MFMA bf16 GEMM (B^T form): C[M][N] = A[M][K]bf16 . Bt[N][K]^T + bias.
// TM x 128 tile, BK=64 (one barrier pair per 64 K), 256 threads.
// LDS rows are 64 elems (128 B = all 32 banks); k-slots XOR-swizzled by row&7.
template<int TM, bool BF16_OUT>
__global__ __launch_bounds__(256) void mfma_gemm_bt(
    const unsigned short* __restrict__ A, const unsigned short* __restrict__ Bt,
    const float* __restrict__ bias, void* __restrict__ Cv, int M, int N)
{
    constexpr int K = KPAD;
    constexpr int RA = TM / 32;            // A staging rounds
    constexpr int MI = 4;
    constexpr int NI = (TM == 128) ? 4 : 2;
    __shared__ unsigned short sA[TM*64];
    __shared__ unsigned short sB[128*64];
    const int tid = threadIdx.x;
    const int m0 = blockIdx.y * TM, n0 = blockIdx.x * 128;
    const int wave = tid >> 6, lane = tid & 63;
    const int wm = (TM == 128) ? (wave & 1) * 64 : 0;
    const int wn = (TM == 128) ? (wave >> 1) * 64 : wave * 32;
    const int lrow = lane & 15, quad = lane >> 4;

    // staging: 8 lanes per row; lane fetches global k-slot g so that it lands
    // (via lane-contiguous glds16) at LDS slot (tid&7) = g ^ (row&7)
    const int sr = tid >> 3;               // 0..31, row within round
    const int g  = (tid & 7) ^ (sr & 7);
    const unsigned short* Ag[RA];
    #pragma unroll
    for (int p = 0; p < RA; ++p)
        Ag[p] = A + (size_t)min(m0 + sr + 32*p, M - 1) * K + g*8;
    const unsigned short* Bg[4];
    #pragma unroll
    for (int p = 0; p < 4; ++p)
        Bg[p] = Bt + (size_t)(n0 + sr + 32*p) * K + g*8;

    // fragment offsets (elements): row*64 + (slot ^ (row&7))*8, slot = h*4+quad.
    // row&7 == lrow&7 for all frag rows; h=1 flips slot bit2 -> offset ^ 32.
    int offA[MI], offB[NI];
    #pragma unroll
    for (int i = 0; i < MI; ++i)
        offA[i] = (wm + i*16 + lrow)*64 + ((quad ^ (lrow & 7)) * 8);
    #pragma unroll
    for (int i = 0; i < NI; ++i)
        offB[i] = (wn + i*16 + lrow)*64 + ((quad ^ (lrow & 7)) * 8);

    f32x4 acc[MI][NI] = {};

    for (int k0 = 0; k0 < K; k0 += 64) {
        #pragma unroll
        for (int p = 0; p < RA; ++p) glds16(Ag[p] + k0, sA + (tid + 256*p)*8);
        #pragma unroll
        for (int p = 0; p < 4;  ++p) glds16(Bg[p] + k0, sB + (tid + 256*p)*8);
        __syncthreads();
        #pragma unroll
        for (int h = 0; h < 2; ++h) {
            const int hx = h * 32;
            bf16x8 af[MI], bfr[NI];
            #pragma unroll
            for (int i = 0; i < MI; ++i) af[i]  = *(const bf16x8*)&sA[offA[i] ^ hx];
            #pragma unroll
            for (int i = 0; i < NI; ++i) bfr[i] = *(const bf16x8*)&sB[offB[i] ^ hx];
            #pragma unroll
            for (int mi = 0; mi < MI; ++mi)
                #pragma unroll
                for (int ni = 0; ni < NI; ++ni)
                    acc[mi][ni] = __builtin_amdgcn_mfma_f32_16x16x32_bf16(
                        af[mi], bfr[ni], acc[mi][ni], 0, 0, 0);
        }
        __syncthreads();
    }

    // epilogue: C/D layout col=lane&15, row=quad*4+reg
    #pragma unroll
    for (int ni = 0; ni < NI; ++ni) {
        int col = n0 + wn + ni*16 + lrow;
        float bv = bias[col];
        #pragma unroll
        for (int mi = 0; mi < MI; ++mi) {
            int rowb = m0 + wm + mi*16 + quad*4;
            #pragma unroll
            for (int r = 0; r < 4; ++r) {
                int row = rowb + r;
                if (row < M) {
                    float v = acc[mi][ni][r] + bv;
                    if (BF16_OUT) ((unsigned short*)Cv)[(size_t)row*N + col] = f2bf(v);
                    else          ((float*)Cv)[(size_t)row*N + col] = v;
                }
            }
        }
    }
}

// RMSNorm in-place on bf16 rows [MROWS][1280], scale by rms_w
__global__ __launch_bounds__(256) void k5_rms_bf16(
    unsigned short* __restrict__ hX, const float* __restrict__ rms_w)
{
    int row = blockIdx.x;
    unsigned short* p = hX + (size_t)row * H_;
    int tid = threadIdx.x;
    float v[5];
    float s = 0.f;
    #pragma unroll
    for (int i = 0; i < 5; ++i) {
        v[i] = bf2f(p[tid + i*256]);
        s += v[i] * v[i];
    }
    __shared__ float red[256];
    red[tid] = s; __syncthreads();
    for (int off = 128; off > 0; off >>= 1) {
        if (tid < off) red[tid] += red[tid+off];
        __syncthreads();
    }
    float inv = 1.f / sqrtf(red[0] / (float)H_ + 1e-6f);
    #pragma unroll
    for (int i = 0; i < 5; ++i) {
        int d = tid + i*256;
        p[d] = f2bf(v[i] * inv * rms_w[d]);
    }
}

extern "C" void kernel_launch(void* const* d_in, const int* in_sizes, int n_in,
                              void* d_out, int out_size, void* d_ws, size_t ws_size,
                              hipStream_t stream) {
    (void)in_sizes; (void)n_in; (void)out_size; (void)ws_size;
    const float* audio      = (const float*)d_in[0];
    const int*   num_tokens = (const int*)d_in[1];
    const float* rms_w      = (const float*)d_in[2];
    const float* cif_w      = (const float*)d_in[3];
    const float* cif_b      = (const float*)d_in[4];
    const float* text_w     = (const float*)d_in[5];
    const float* text_b     = (const float*)d_in[6];

    float* out  = (float*)d_out;                   // fp32 output
    float* pred = out + (size_t)MROWS * OUT_;      // pred_num_tokens tail (8 floats)

    char* ws = (char*)d_ws;
    float* w0a    = (float*)(ws + 48000);
    float* w1a    = (float*)(ws + 96000);
    int*   tok0   = (int*)  (ws + 144000);
    int*   tok1   = (int*)  (ws + 192000);
    int*   lo     = (int*)  (ws + 240000);     // 12000 B
    int*   hi     = (int*)  (ws + 252000);     // -> 264000, pad to 264192
    // DISJOINT regions (no lifetime aliasing — round-5 lesson):
    unsigned short* h1b = (unsigned short*)(ws + 264192);     //  7,680,000 B
    unsigned short* cwt = (unsigned short*)(ws + 7944192);    //  3,276,800 B
    unsigned short* twt = (unsigned short*)(ws + 11220992);   // 10,485,760 B
    unsigned short* hX  = (unsigned short*)(ws + 21706752);   //  7,680,000 B (cif out, rmsnorm in-place)
    // total ws usage: 29,386,752 B (<= 30.97 MB proven in round 2)

    // scan (blocks 0..7) + both weight transposes (blocks 8..6727)
    k_front<<<B_ + 1600 + 5120, 256, 0, stream>>>(
        audio, num_tokens, pred, tok0, w0a, tok1, w1a, lo, hi,
        cif_w, text_w, cwt, twt);
    k3_pool<<<MROWS, 256, 0, stream>>>(audio, tok0, w0a, tok1, w1a, lo, hi, h1b);
    // cif_proj (bf16 out): hX = h1b[3000x1280] . cwt^T + cif_b   (64-row tiles -> 470 blocks)
    mfma_gemm_bt<64, true><<<dim3(H_/128, (MROWS+63)/64), 256, 0, stream>>>(
        h1b, cwt, cif_b, hX, MROWS, H_);
    k5_rms_bf16<<<MROWS, 256, 0, stream>>>(hX, rms_w);
    // text_proj: out = hX[3000x1280] . twt^T + text_b
    mfma_gemm_bt<128, false><<<dim3(OUT_/128, (MROWS+127)/128), 256, 0, stream>>>(
        hX, twt, text_b, out, MROWS, OUT_);
}